// Round 4
// baseline (856.084 us; speedup 1.0000x reference)
//
#include <hip/hip_runtime.h>
#include <math.h>

#define BB 8
#define CC 512
#define HWN 4096

typedef __bf16 bf16x8 __attribute__((ext_vector_type(8)));
typedef __bf16 bf16x4 __attribute__((ext_vector_type(4)));
typedef float f32x4 __attribute__((ext_vector_type(4)));

#define GLOBAL_AS __attribute__((address_space(1)))
#define LDS_AS __attribute__((address_space(3)))

static __device__ __forceinline__ void async_copy16(const void* g, void* l) {
  __builtin_amdgcn_global_load_lds((const GLOBAL_AS unsigned int*)g,
                                   (LDS_AS unsigned int*)l, 16, 0, 0);
}

// ---------------------------------------------------------------------------
// v5: 256x256-tile 8-wave GEMM, 2 LDS buffers -> 64 KiB -> 2 blocks/CU.
// v4 post-mortem: 4-buf/128KiB forced 1 block/CU; the per-phase barrier
// lockstep serialized LDS (768cy/tile) and MFMA (1240cy/tile) with nothing
// to fill the gaps -> MfmaUtil pinned at 23%. m114/m97 show the win comes
// from CO-RESIDENT blocks overlapping phases. Structure per K-tile:
//   vmcnt(0)   -- waits stage(t), issued one full tile of compute earlier
//   s_barrier  -- all waves' staged halves resident; all t-1 reads done
//   stage(t+1) -- into buf[(t+1)&1] (last read at t-1: safe post-barrier)
//   ds_read 12 b128 frags; compiler emits fine-grained lgkmcnt (m97)
//   setprio(1) 32 MFMA setprio(0)
// One barrier per tile (was 6). The boundary vmcnt(0) is ~free (issue-to-
// wait distance ~1500cy > HBM latency) and any residue is covered by the
// second block on the CU.  Waves 2M x 4N; per-wave output 128x64 acc[8][4].
// Split-K: grid.z = batch*ksl + slice; slice output at Cg + slice*sSlice.
// ---------------------------------------------------------------------------
template <int BIASMODE, typename OUT_T>
__global__ __launch_bounds__(512, 4) void gemm256_mfma_bt(
    const __bf16* __restrict__ Ag, const __bf16* __restrict__ Bg,
    const float* __restrict__ bias, OUT_T* __restrict__ Cg,
    int M, int N, int K, long sA, long sB, long sC, float alpha,
    int ksl, long sSlice) {
  __shared__ __align__(16) __bf16 As[2][256][32];  // 32 KiB
  __shared__ __align__(16) __bf16 Bs[2][256][32];  // 32 KiB

  const int tid = threadIdx.x;
  const int n0 = blockIdx.x * 256;
  const int m0 = blockIdx.y * 256;
  const int bz = blockIdx.z;
  const int batch = bz / ksl;
  const int slice = bz - batch * ksl;
  const int kLen = K / ksl;
  const int kBeg = slice * kLen;
  const int NT = kLen >> 5;  // K-tiles of 32 (all call sites: NT == 16)
  Ag += (long)batch * sA;
  Bg += (long)batch * sB;
  Cg += (long)batch * sC + (long)slice * sSlice;

  const int lane = tid & 63;
  const int w = tid >> 6;   // 0..7
  const int wr = w >> 2;    // m-half 0..1
  const int wn = w & 3;     // n-quarter 0..3
  const int l15 = lane & 15, quad = lane >> 4;

  // Staging map: thread tid covers LDS bytes [tid*16,+16) of each 8KB step;
  // step s covers rows s*128..s*128+127. row = s*128 + (tid>>2), seg tid&3.
  // LDS dest = wave-uniform base + lane*16 (global_load_lds requirement).
  const __bf16* Arow = Ag + (long)(m0 + (tid >> 2)) * K + (tid & 3) * 8;
  const __bf16* Brow = Bg + (long)(n0 + (tid >> 2)) * K + (tid & 3) * 8;

  f32x4 acc[8][4] = {};

  auto stageA = [&](int t) {
    const int b = t & 1;
    const int kk = kBeg + t * 32;
#pragma unroll
    for (int s = 0; s < 2; s++)
      async_copy16(Arow + (long)s * 128 * K + kk,
                   (char*)&As[b][0][0] + s * 8192 + tid * 16);
  };
  auto stageB = [&](int t) {
    const int b = t & 1;
    const int kk = kBeg + t * 32;
#pragma unroll
    for (int s = 0; s < 2; s++)
      async_copy16(Brow + (long)s * 128 * K + kk,
                   (char*)&Bs[b][0][0] + s * 8192 + tid * 16);
  };

  stageA(0); stageB(0);

  for (int t = 0; t < NT; t++) {
    const int b = t & 1;
    // My stage(t) loads are the only outstanding VMEM: drain them. They
    // were issued ~1 K-tile of compute ago, so this is normally satisfied.
    asm volatile("s_waitcnt vmcnt(0)" ::: "memory");
    __builtin_amdgcn_s_barrier();      // all halves resident; t-1 reads done
    __builtin_amdgcn_sched_barrier(0); // no ds_read may hoist above barrier

    if (t + 1 < NT) { stageA(t + 1); stageB(t + 1); }

    const __bf16(*Asb)[32] = As[b];
    const __bf16(*Bsb)[32] = Bs[b];

    bf16x8 bfr[4], af[4], af2[4];
#pragma unroll
    for (int nj = 0; nj < 4; nj++)
      bfr[nj] = *(const bf16x8*)&Bsb[wn * 64 + nj * 16 + l15][quad * 8];
#pragma unroll
    for (int mi = 0; mi < 4; mi++)
      af[mi] = *(const bf16x8*)&Asb[wr * 128 + mi * 16 + l15][quad * 8];
    __builtin_amdgcn_s_setprio(1);
#pragma unroll
    for (int mi = 0; mi < 4; mi++)
#pragma unroll
      for (int nj = 0; nj < 4; nj++)
        acc[mi][nj] = __builtin_amdgcn_mfma_f32_16x16x32_bf16(
            af[mi], bfr[nj], acc[mi][nj], 0, 0, 0);
    __builtin_amdgcn_s_setprio(0);
#pragma unroll
    for (int mi = 0; mi < 4; mi++)
      af2[mi] = *(const bf16x8*)&Asb[wr * 128 + 64 + mi * 16 + l15][quad * 8];
    __builtin_amdgcn_s_setprio(1);
#pragma unroll
    for (int mi = 0; mi < 4; mi++)
#pragma unroll
      for (int nj = 0; nj < 4; nj++)
        acc[mi + 4][nj] = __builtin_amdgcn_mfma_f32_16x16x32_bf16(
            af2[mi], bfr[nj], acc[mi + 4][nj], 0, 0, 0);
    __builtin_amdgcn_s_setprio(0);
  }

#pragma unroll
  for (int mi = 0; mi < 8; mi++) {
#pragma unroll
    for (int nj = 0; nj < 4; nj++) {
#pragma unroll
      for (int r = 0; r < 4; r++) {
        const int m = m0 + wr * 128 + mi * 16 + quad * 4 + r;
        const int n = n0 + wn * 64 + nj * 16 + l15;
        float v = acc[mi][nj][r];
        if (BIASMODE == 1) v += bias[m];
        Cg[(long)m * N + n] = (OUT_T)(v * alpha);
      }
    }
  }
}

// ---------------------------------------------------------------------------
// 128^2 4-wave GEMM (v3 deep-pipeline) — retained ONLY for step 6 (small
// grid: 128 blocks; 256^2 would give 32 blocks). Verified correct in R2/R3.
// ---------------------------------------------------------------------------
template <int BIASMODE, typename OUT_T>
__global__ __launch_bounds__(256) void gemm_mfma_bt(
    const __bf16* __restrict__ Ag, const __bf16* __restrict__ Bg,
    const float* __restrict__ bias, OUT_T* __restrict__ Cg,
    int M, int N, int K, long sA, long sB, long sC, float alpha,
    int ksl, long sSlice) {
  __shared__ __align__(16) __bf16 As[4][128][32];
  __shared__ __align__(16) __bf16 Bs[4][128][32];

  const int tid = threadIdx.x;
  const int n0 = blockIdx.x * 128;
  const int m0 = blockIdx.y * 128;
  const int bz = blockIdx.z;
  const int batch = bz / ksl;
  const int slice = bz - batch * ksl;
  const int kLen = K / ksl;
  const int kBeg = slice * kLen;
  const int NT = kLen >> 5;
  Ag += (long)batch * sA;
  Bg += (long)batch * sB;
  Cg += (long)batch * sC + (long)slice * sSlice;

  const int lane = tid & 63;
  const int w = tid >> 6;
  const int wr = w >> 1, wc = w & 1;
  const int l15 = lane & 15, quad = lane >> 4;

  const int srow = tid >> 2;
  const int scol = (tid & 3) * 8;
  const __bf16* Arow = Ag + (long)(m0 + srow) * K + scol;
  const __bf16* Brow = Bg + (long)(n0 + srow) * K + scol;

  f32x4 acc[4][4] = {};

  auto stageT = [&](int t) {
    const int b = t & 3;
    const int kk = kBeg + t * 32;
#pragma unroll
    for (int s = 0; s < 2; s++) {
      async_copy16(Arow + (long)s * 64 * K + kk,
                   (char*)&As[b][0][0] + s * 4096 + tid * 16);
      async_copy16(Brow + (long)s * 64 * K + kk,
                   (char*)&Bs[b][0][0] + s * 4096 + tid * 16);
    }
  };

  stageT(0);
  if (NT > 1) stageT(1);
  if (NT > 2) stageT(2);

  for (int t = 0; t < NT; t++) {
    if (t < NT - 2)
      asm volatile("s_waitcnt vmcnt(8)" ::: "memory");
    else if (t == NT - 2)
      asm volatile("s_waitcnt vmcnt(4)" ::: "memory");
    else
      asm volatile("s_waitcnt vmcnt(0)" ::: "memory");
    __builtin_amdgcn_s_barrier();
    __builtin_amdgcn_sched_barrier(0);

    if (t + 3 < NT) stageT(t + 3);

    const int b = t & 3;
    bf16x8 af[4], bfr[4];
#pragma unroll
    for (int u = 0; u < 4; u++) {
      af[u]  = *(const bf16x8*)&As[b][wr * 64 + u * 16 + l15][quad * 8];
      bfr[u] = *(const bf16x8*)&Bs[b][wc * 64 + u * 16 + l15][quad * 8];
    }
    __builtin_amdgcn_s_setprio(1);
#pragma unroll
    for (int ti = 0; ti < 4; ti++)
#pragma unroll
      for (int tj = 0; tj < 4; tj++)
        acc[ti][tj] = __builtin_amdgcn_mfma_f32_16x16x32_bf16(
            af[ti], bfr[tj], acc[ti][tj], 0, 0, 0);
    __builtin_amdgcn_s_setprio(0);
  }

#pragma unroll
  for (int ti = 0; ti < 4; ti++) {
#pragma unroll
    for (int tj = 0; tj < 4; tj++) {
#pragma unroll
      for (int r = 0; r < 4; r++) {
        const int m = m0 + wr * 64 + ti * 16 + quad * 4 + r;
        const int n = n0 + wc * 64 + tj * 16 + l15;
        float v = acc[ti][tj][r];
        if (BIASMODE == 1) v += bias[m];
        Cg[(long)m * N + n] = (OUT_T)(v * alpha);
      }
    }
  }
}

// ---------------------------------------------------------------------------
// Dual softmax over bf16 logit rows [B,1024,HWN] in d_out.
// Row c<512 (B-logits): write normalized bf16 row to bm[b,c,:].
// Row c>=512 (V-logits): write back in place (av).
// ---------------------------------------------------------------------------
__global__ __launch_bounds__(256) void softmax_dual_bf16(
    __bf16* __restrict__ logits, __bf16* __restrict__ bm) {
  const int row = blockIdx.x;                 // 0..8191
  const int b = row >> 10, c = row & 1023;
  __bf16* src = logits + ((long)b * 1024 + c) * HWN;
  __bf16* dst = (c < 512) ? (bm + ((long)b * 512 + c) * HWN) : src;
  const int tid = threadIdx.x;

  const bf16x8* p = reinterpret_cast<const bf16x8*>(src);
  bf16x8* q = reinterpret_cast<bf16x8*>(dst);

  float v[16];
  float vmax = -3.0e38f;
#pragma unroll
  for (int i = 0; i < 2; i++) {
    bf16x8 t = p[tid + i * 256];
#pragma unroll
    for (int j = 0; j < 8; j++) {
      v[i * 8 + j] = (float)t[j];
      vmax = fmaxf(vmax, v[i * 8 + j]);
    }
  }
#pragma unroll
  for (int off = 32; off > 0; off >>= 1)
    vmax = fmaxf(vmax, __shfl_xor(vmax, off, 64));

  __shared__ float red[4];
  const int wid = tid >> 6;
  if ((tid & 63) == 0) red[wid] = vmax;
  __syncthreads();
  vmax = fmaxf(fmaxf(red[0], red[1]), fmaxf(red[2], red[3]));
  __syncthreads();

  float s = 0.f;
#pragma unroll
  for (int i = 0; i < 16; i++) {
    v[i] = expf(v[i] - vmax);
    s += v[i];
  }
#pragma unroll
  for (int off = 32; off > 0; off >>= 1) s += __shfl_xor(s, off, 64);
  if ((tid & 63) == 0) red[wid] = s;
  __syncthreads();
  s = (red[0] + red[1]) + (red[2] + red[3]);

  const float inv = 1.0f / s;
#pragma unroll
  for (int i = 0; i < 2; i++) {
    bf16x8 o;
#pragma unroll
    for (int j = 0; j < 8; j++) o[j] = (__bf16)(v[i * 8 + j] * inv);
    q[tid + i * 256] = o;
  }
}

// ---------------------------------------------------------------------------
// Reduce bf16 split-K partials (8 slices of 262144 elems per batch, batch
// stride 2097152) -> bf16 Mb. One thread = 8 output elems.
// ---------------------------------------------------------------------------
__global__ __launch_bounds__(256) void reduce_partials8b(
    const __bf16* __restrict__ P, __bf16* __restrict__ out) {
  const long i = ((long)blockIdx.x * 256 + threadIdx.x) * 8;  // < 2M
  const int b = (int)(i >> 18);
  const long il = i & 262143;
  const __bf16* p = P + (long)b * 2097152 + il;
  float s[8] = {};
#pragma unroll
  for (int sl = 0; sl < 8; sl++) {
    bf16x8 t = *(const bf16x8*)&p[(long)sl * 262144];
#pragma unroll
    for (int j = 0; j < 8; j++) s[j] += (float)t[j];
  }
  bf16x8 o;
#pragma unroll
  for (int j = 0; j < 8; j++) o[j] = (__bf16)s[j];
  *(bf16x8*)&out[i] = o;
}

// ---------------------------------------------------------------------------
// z<8:  x (fp32 [C,HW] batch z) -> xb (bf16 same layout) + xT (bf16 [HW,C]).
// z==8: weight/bias conversion (wB,wV -> wBVb stacked; wA -> wAb; bBV pack).
// ---------------------------------------------------------------------------
__global__ __launch_bounds__(256) void convert_all(
    const float* __restrict__ x, __bf16* __restrict__ xb,
    __bf16* __restrict__ xT, const float* __restrict__ wA,
    const float* __restrict__ wB, const float* __restrict__ wV,
    const float* __restrict__ bB, const float* __restrict__ bV,
    __bf16* __restrict__ wAb, __bf16* __restrict__ wBVb,
    float* __restrict__ bBV) {
  if (blockIdx.z == 8) {
    const int t = blockIdx.y * 64 + blockIdx.x;  // 0..511
    const int grp = t >> 7;                      // 128 blocks per matrix
    const int r = t & 127;
    if (grp == 3) {
      if (r == 0) {
#pragma unroll
        for (int j = 0; j < 4; j++) {
          const int i = threadIdx.x * 4 + j;
          bBV[i] = (i < 512) ? bB[i] : bV[i - 512];
        }
      }
      return;
    }
    const float* in = grp == 0 ? wB : (grp == 1 ? wV : wA);
    __bf16* o = grp == 0 ? wBVb : (grp == 1 ? wBVb + 262144 : wAb);
    const long base = (long)r * 2048 + threadIdx.x * 8;  // 2048 elems/block
    float4 v0 = *(const float4*)&in[base];
    float4 v1 = *(const float4*)&in[base + 4];
    bf16x8 ob;
    ob[0] = (__bf16)v0.x; ob[1] = (__bf16)v0.y; ob[2] = (__bf16)v0.z;
    ob[3] = (__bf16)v0.w; ob[4] = (__bf16)v1.x; ob[5] = (__bf16)v1.y;
    ob[6] = (__bf16)v1.z; ob[7] = (__bf16)v1.w;
    *(bf16x8*)&o[base] = ob;
    return;
  }

  __shared__ __bf16 t[64][66];
  const int j0 = blockIdx.x * 64;
  const int c0 = blockIdx.y * 64;
  const long bofs = (long)blockIdx.z * CC * HWN;
  const int j = threadIdx.x & 63;
  const int g = threadIdx.x >> 6;

#pragma unroll
  for (int r = 0; r < 16; r++) {
    const int i = r * 4 + g;
    const float v = x[bofs + (long)(c0 + i) * HWN + j0 + j];
    const __bf16 bv = (__bf16)v;
    xb[bofs + (long)(c0 + i) * HWN + j0 + j] = bv;
    t[j][i] = bv;
  }
  __syncthreads();
#pragma unroll
  for (int r = 0; r < 16; r++) {
    const int jj = r * 4 + g;
    xT[bofs + (long)(j0 + jj) * CC + c0 + j] = t[jj][j];
  }
}

// bf16 transpose: out[b*sOut + j*CC + c] = in[b*sIn + c*ldIn + j]
__global__ __launch_bounds__(256) void transpose_bf16_s(
    const __bf16* __restrict__ in, __bf16* __restrict__ out, int ldIn,
    long sIn, long sOut) {
  __shared__ __bf16 t[64][66];
  const int j0 = blockIdx.x * 64;
  const int c0 = blockIdx.y * 64;
  const int j = threadIdx.x & 63;
  const int g = threadIdx.x >> 6;

#pragma unroll
  for (int r = 0; r < 16; r++) {
    const int i = r * 4 + g;
    t[j][i] = in[(long)blockIdx.z * sIn + (long)(c0 + i) * ldIn + j0 + j];
  }
  __syncthreads();
#pragma unroll
  for (int r = 0; r < 16; r++) {
    const int jj = r * 4 + g;
    out[(long)blockIdx.z * sOut + (long)(j0 + jj) * CC + c0 + j] = t[jj][j];
  }
}

// ---------------------------------------------------------------------------
// Plan:
//  0. convert_all: x->xb,xT; weights->bf16 (stacked wBV); biases packed
//  1. logits = wBV·x + bBV  (M=1024)  [gemm256]      -> d_out bf16 [B,1024,HW]
//  2. softmax_dual: B-rows -> bm (ws), V-rows -> in place (av)
//  3. transpose av -> avT into xT region (xT dead)
//  4. M partials split-K=8 (A=bm,B=xb) [gemm256]     -> d_out bf16 (32 MiB)
//  5. reduce -> Mb bf16
//  6. gdT = (wA·M^T + bA)/HW (A=wAb,B=Mb) [gemm128]  -> gdT bf16
//  7. out = gdT·avT          (A=gdT,B=xT) [gemm256]  -> d_out fp32 (full 64MB)
// ---------------------------------------------------------------------------
extern "C" void kernel_launch(void* const* d_in, const int* in_sizes, int n_in,
                              void* d_out, int out_size, void* d_ws,
                              size_t ws_size, hipStream_t stream) {
  const float* x  = (const float*)d_in[0];
  const float* wA = (const float*)d_in[1];
  const float* bA = (const float*)d_in[2];
  const float* wB = (const float*)d_in[3];
  const float* bB = (const float*)d_in[4];
  const float* wV = (const float*)d_in[5];
  const float* bV = (const float*)d_in[6];
  float* out = (float*)d_out;

  const size_t nBCHW = (size_t)BB * CC * HWN;   // 16M
  const size_t nBCC  = (size_t)BB * CC * CC;    // 2M
  __bf16* xb   = (__bf16*)d_ws;          // [B,C,HW]
  __bf16* xT   = xb + nBCHW;             // [B,HW,C]; later avT
  __bf16* bm   = xT + nBCHW;             // [B,C,HW]
  __bf16* Mb   = bm + nBCHW;             // [B,C,C]
  __bf16* gdT  = Mb + nBCC;              // [B,C,C]
  __bf16* wBVb = gdT + nBCC;             // [1024,512]
  __bf16* wAb  = wBVb + (size_t)1024 * CC;
  float*  bBV  = (float*)(wAb + (size_t)CC * CC);  // [1024]

  const long sBC_HW = (long)CC * HWN;    // 2097152
  const long sCC = (long)CC * CC;        // 262144

  convert_all<<<dim3(HWN / 64, CC / 64, BB + 1), 256, 0, stream>>>(
      x, xb, xT, wA, wB, wV, bB, bV, wAb, wBVb, bBV);

  __bf16* logits = (__bf16*)d_out;       // [B,1024,HW] bf16 == 64 MiB

  // 1. merged logits GEMM (M=1024): rows 0-511 B-logits, 512-1023 V-logits
  gemm256_mfma_bt<1, __bf16>
      <<<dim3(HWN / 256, 1024 / 256, BB), 512, 0, stream>>>(
          wBVb, xT, bBV, logits, 1024, HWN, CC, 0, sBC_HW, (long)1024 * HWN,
          1.0f, 1, 0);
  // 2. dual softmax
  softmax_dual_bf16<<<dim3(BB * 1024), 256, 0, stream>>>(logits, bm);
  // 3. avT (av rows live at logits + b*4194304 + 2097152 + c*4096)
  transpose_bf16_s<<<dim3(HWN / 64, CC / 64, BB), 256, 0, stream>>>(
      logits + 2097152, xT, HWN, (long)1024 * HWN, (long)HWN * CC);
  // 4. M split-K=8 partials -> d_out as bf16: batch 2097152, slice 262144
  gemm256_mfma_bt<0, __bf16><<<dim3(CC / 256, CC / 256, BB * 8), 512, 0,
                               stream>>>(bm, xb, nullptr, (__bf16*)out, CC,
                                         CC, HWN, sBC_HW, sBC_HW,
                                         (long)2097152, 1.0f, 8,
                                         (long)262144);
  // 5. reduce -> Mb
  reduce_partials8b<<<dim3(1024), 256, 0, stream>>>((const __bf16*)out, Mb);
  // 6. gdT = (wA @ M^T + bA)/HW  (small grid -> 128^2 kernel)
  gemm_mfma_bt<1, __bf16><<<dim3(CC / 128, CC / 128, BB), 256, 0, stream>>>(
      wAb, Mb, bA, gdT, CC, CC, CC, 0, sCC, sCC, 1.0f / (float)HWN, 1, 0);
  // 7. out = gdT @ avT -> d_out (fp32, overwrites everything)
  gemm256_mfma_bt<0, float>
      <<<dim3(HWN / 256, CC / 256, BB), 512, 0, stream>>>(
          gdT, xT, nullptr, out, CC, HWN, CC, sCC, sBC_HW, sBC_HW, 1.0f, 1,
          0);
}

// Round 5
// 292.882 us; speedup vs baseline: 2.9230x; 2.9230x over previous
//
#include <hip/hip_runtime.h>
#include <math.h>

#define BB 8
#define CC 512
#define HWN 4096

typedef __bf16 bf16x8 __attribute__((ext_vector_type(8)));
typedef __bf16 bf16x4 __attribute__((ext_vector_type(4)));
typedef float f32x4 __attribute__((ext_vector_type(4)));

#define GLOBAL_AS __attribute__((address_space(1)))
#define LDS_AS __attribute__((address_space(3)))

static __device__ __forceinline__ void async_copy16(const void* g, void* l) {
  __builtin_amdgcn_global_load_lds((const GLOBAL_AS unsigned int*)g,
                                   (LDS_AS unsigned int*)l, 16, 0, 0);
}

// ---------------------------------------------------------------------------
// v6: 256x256-tile 8-wave GEMM, BT form:
//   C[m,n] = alpha*(sum_k A[m,k]*B[n,k] + bias[m]?)
// R4 post-mortem: __launch_bounds__(512,4) demanded 128 regs/wave; acc[8][4]
// alone is 128 -> compiler spilled acc to scratch (VGPR 64, FETCH 424MB,
// WRITE 790MB, MfmaUtil 4%). A 256^2 tile can NEVER be 2 blocks/CU
// (16 waves x ~210 regs > 2048 pool). So: accept 1 block/CU and minimize
// sync overhead instead (R3's 6 barriers/tile lockstep = 4100 cy/tile vs
// ~500 ideal). Structure per K-tile t (ONE barrier):
//   vmcnt(4)   -- counted: retires exactly stage(t)'s 4 loads; stage(t+1),
//                 stage(t+2) stay in flight across the barrier (T4)
//   s_barrier  -- tile t resident for all; all t-1 reads done
//   sched_barrier(0) -- pins stage/ds_read below (hoist would race t-1 reads)
//   stage(t+2) -- into buf[(t+2)%3]; last read at t-1: safe post-barrier
//   12x ds_read_b128 + 32 MFMA, one region -- compiler interleaves with
//   fine-grained lgkmcnt (m97 asm evidence), setprio(1) on MFMA cluster
// 3 LDS buffers (96 KiB, free at 1 block/CU) give lead-2 prefetch: issue-to-
// wait distance ~2 tiles of compute >> HBM latency.
// Waves 2M x 4N; per-wave output 128x64 = acc[8][4].
// Split-K: grid.z = batch*ksl + slice; slice output at Cg + slice*sSlice.
// ---------------------------------------------------------------------------
template <int BIASMODE, typename OUT_T>
__global__ __launch_bounds__(512, 2) void gemm256_mfma_bt(
    const __bf16* __restrict__ Ag, const __bf16* __restrict__ Bg,
    const float* __restrict__ bias, OUT_T* __restrict__ Cg,
    int M, int N, int K, long sA, long sB, long sC, float alpha,
    int ksl, long sSlice) {
  __shared__ __align__(16) __bf16 As[3][256][32];  // 48 KiB
  __shared__ __align__(16) __bf16 Bs[3][256][32];  // 48 KiB

  const int tid = threadIdx.x;
  const int n0 = blockIdx.x * 256;
  const int m0 = blockIdx.y * 256;
  const int bz = blockIdx.z;
  const int batch = bz / ksl;
  const int slice = bz - batch * ksl;
  const int kLen = K / ksl;
  const int kBeg = slice * kLen;
  const int NT = kLen >> 5;  // K-tiles of 32 (all call sites: NT == 16)
  Ag += (long)batch * sA;
  Bg += (long)batch * sB;
  Cg += (long)batch * sC + (long)slice * sSlice;

  const int lane = tid & 63;
  const int w = tid >> 6;   // 0..7
  const int wr = w >> 2;    // m-half 0..1
  const int wn = w & 3;     // n-quarter 0..3
  const int l15 = lane & 15, quad = lane >> 4;

  // Staging map: thread tid covers LDS bytes [tid*16,+16) of each 8KB step;
  // step s covers rows s*128..s*128+127. row = s*128 + (tid>>2), seg tid&3.
  // LDS dest = wave-uniform base + lane*16 (global_load_lds requirement).
  const __bf16* Arow = Ag + (long)(m0 + (tid >> 2)) * K + (tid & 3) * 8;
  const __bf16* Brow = Bg + (long)(n0 + (tid >> 2)) * K + (tid & 3) * 8;

  f32x4 acc[8][4] = {};

  auto stageT = [&](int t) {
    const int b = t % 3;
    const int kk = kBeg + t * 32;
#pragma unroll
    for (int s = 0; s < 2; s++) {
      async_copy16(Arow + (long)s * 128 * K + kk,
                   (char*)&As[b][0][0] + s * 8192 + tid * 16);
      async_copy16(Brow + (long)s * 128 * K + kk,
                   (char*)&Bs[b][0][0] + s * 8192 + tid * 16);
    }
  };

  // prologue: tiles 0,1 issued (8 loads in flight)
  stageT(0);
  stageT(1);

  for (int t = 0; t < NT; t++) {
    // Counted wait: retire exactly tile t's 4 loads (oldest; vmcnt retires
    // in order, m135). Tiles t+1/t+2 stay in flight across the barrier.
    if (t < NT - 1)
      asm volatile("s_waitcnt vmcnt(4)" ::: "memory");
    else
      asm volatile("s_waitcnt vmcnt(0)" ::: "memory");
    __builtin_amdgcn_s_barrier();      // tile t resident; t-1 reads done
    __builtin_amdgcn_sched_barrier(0); // nothing may hoist above barrier

    if (t + 2 < NT) stageT(t + 2);

    const __bf16(*Asb)[32] = As[t % 3];
    const __bf16(*Bsb)[32] = Bs[t % 3];

    bf16x8 bfr[4], af[4], af2[4];
#pragma unroll
    for (int nj = 0; nj < 4; nj++)
      bfr[nj] = *(const bf16x8*)&Bsb[wn * 64 + nj * 16 + l15][quad * 8];
#pragma unroll
    for (int mi = 0; mi < 4; mi++)
      af[mi] = *(const bf16x8*)&Asb[wr * 128 + mi * 16 + l15][quad * 8];
#pragma unroll
    for (int mi = 0; mi < 4; mi++)
      af2[mi] = *(const bf16x8*)&Asb[wr * 128 + 64 + mi * 16 + l15][quad * 8];

    __builtin_amdgcn_s_setprio(1);
#pragma unroll
    for (int mi = 0; mi < 4; mi++)
#pragma unroll
      for (int nj = 0; nj < 4; nj++)
        acc[mi][nj] = __builtin_amdgcn_mfma_f32_16x16x32_bf16(
            af[mi], bfr[nj], acc[mi][nj], 0, 0, 0);
#pragma unroll
    for (int mi = 0; mi < 4; mi++)
#pragma unroll
      for (int nj = 0; nj < 4; nj++)
        acc[mi + 4][nj] = __builtin_amdgcn_mfma_f32_16x16x32_bf16(
            af2[mi], bfr[nj], acc[mi + 4][nj], 0, 0, 0);
    __builtin_amdgcn_s_setprio(0);
  }

#pragma unroll
  for (int mi = 0; mi < 8; mi++) {
#pragma unroll
    for (int nj = 0; nj < 4; nj++) {
#pragma unroll
      for (int r = 0; r < 4; r++) {
        const int m = m0 + wr * 128 + mi * 16 + quad * 4 + r;
        const int n = n0 + wn * 64 + nj * 16 + l15;
        float v = acc[mi][nj][r];
        if (BIASMODE == 1) v += bias[m];
        Cg[(long)m * N + n] = (OUT_T)(v * alpha);
      }
    }
  }
}

// ---------------------------------------------------------------------------
// 128^2 4-wave GEMM (v3 deep-pipeline) — retained ONLY for step 6 (small
// grid: 128 blocks; 256^2 would give 32 blocks). Verified correct in R2/R3.
// ---------------------------------------------------------------------------
template <int BIASMODE, typename OUT_T>
__global__ __launch_bounds__(256) void gemm_mfma_bt(
    const __bf16* __restrict__ Ag, const __bf16* __restrict__ Bg,
    const float* __restrict__ bias, OUT_T* __restrict__ Cg,
    int M, int N, int K, long sA, long sB, long sC, float alpha,
    int ksl, long sSlice) {
  __shared__ __align__(16) __bf16 As[4][128][32];
  __shared__ __align__(16) __bf16 Bs[4][128][32];

  const int tid = threadIdx.x;
  const int n0 = blockIdx.x * 128;
  const int m0 = blockIdx.y * 128;
  const int bz = blockIdx.z;
  const int batch = bz / ksl;
  const int slice = bz - batch * ksl;
  const int kLen = K / ksl;
  const int kBeg = slice * kLen;
  const int NT = kLen >> 5;
  Ag += (long)batch * sA;
  Bg += (long)batch * sB;
  Cg += (long)batch * sC + (long)slice * sSlice;

  const int lane = tid & 63;
  const int w = tid >> 6;
  const int wr = w >> 1, wc = w & 1;
  const int l15 = lane & 15, quad = lane >> 4;

  const int srow = tid >> 2;
  const int scol = (tid & 3) * 8;
  const __bf16* Arow = Ag + (long)(m0 + srow) * K + scol;
  const __bf16* Brow = Bg + (long)(n0 + srow) * K + scol;

  f32x4 acc[4][4] = {};

  auto stageT = [&](int t) {
    const int b = t & 3;
    const int kk = kBeg + t * 32;
#pragma unroll
    for (int s = 0; s < 2; s++) {
      async_copy16(Arow + (long)s * 64 * K + kk,
                   (char*)&As[b][0][0] + s * 4096 + tid * 16);
      async_copy16(Brow + (long)s * 64 * K + kk,
                   (char*)&Bs[b][0][0] + s * 4096 + tid * 16);
    }
  };

  stageT(0);
  if (NT > 1) stageT(1);
  if (NT > 2) stageT(2);

  for (int t = 0; t < NT; t++) {
    if (t < NT - 2)
      asm volatile("s_waitcnt vmcnt(8)" ::: "memory");
    else if (t == NT - 2)
      asm volatile("s_waitcnt vmcnt(4)" ::: "memory");
    else
      asm volatile("s_waitcnt vmcnt(0)" ::: "memory");
    __builtin_amdgcn_s_barrier();
    __builtin_amdgcn_sched_barrier(0);

    if (t + 3 < NT) stageT(t + 3);

    const int b = t & 3;
    bf16x8 af[4], bfr[4];
#pragma unroll
    for (int u = 0; u < 4; u++) {
      af[u]  = *(const bf16x8*)&As[b][wr * 64 + u * 16 + l15][quad * 8];
      bfr[u] = *(const bf16x8*)&Bs[b][wc * 64 + u * 16 + l15][quad * 8];
    }
    __builtin_amdgcn_s_setprio(1);
#pragma unroll
    for (int ti = 0; ti < 4; ti++)
#pragma unroll
      for (int tj = 0; tj < 4; tj++)
        acc[ti][tj] = __builtin_amdgcn_mfma_f32_16x16x32_bf16(
            af[ti], bfr[tj], acc[ti][tj], 0, 0, 0);
    __builtin_amdgcn_s_setprio(0);
  }

#pragma unroll
  for (int ti = 0; ti < 4; ti++) {
#pragma unroll
    for (int tj = 0; tj < 4; tj++) {
#pragma unroll
      for (int r = 0; r < 4; r++) {
        const int m = m0 + wr * 64 + ti * 16 + quad * 4 + r;
        const int n = n0 + wc * 64 + tj * 16 + l15;
        float v = acc[ti][tj][r];
        if (BIASMODE == 1) v += bias[m];
        Cg[(long)m * N + n] = (OUT_T)(v * alpha);
      }
    }
  }
}

// ---------------------------------------------------------------------------
// Dual softmax over bf16 logit rows [B,1024,HWN] in d_out.
// Row c<512 (B-logits): write normalized bf16 row to bm[b,c,:].
// Row c>=512 (V-logits): write back in place (av).
// ---------------------------------------------------------------------------
__global__ __launch_bounds__(256) void softmax_dual_bf16(
    __bf16* __restrict__ logits, __bf16* __restrict__ bm) {
  const int row = blockIdx.x;                 // 0..8191
  const int b = row >> 10, c = row & 1023;
  __bf16* src = logits + ((long)b * 1024 + c) * HWN;
  __bf16* dst = (c < 512) ? (bm + ((long)b * 512 + c) * HWN) : src;
  const int tid = threadIdx.x;

  const bf16x8* p = reinterpret_cast<const bf16x8*>(src);
  bf16x8* q = reinterpret_cast<bf16x8*>(dst);

  float v[16];
  float vmax = -3.0e38f;
#pragma unroll
  for (int i = 0; i < 2; i++) {
    bf16x8 t = p[tid + i * 256];
#pragma unroll
    for (int j = 0; j < 8; j++) {
      v[i * 8 + j] = (float)t[j];
      vmax = fmaxf(vmax, v[i * 8 + j]);
    }
  }
#pragma unroll
  for (int off = 32; off > 0; off >>= 1)
    vmax = fmaxf(vmax, __shfl_xor(vmax, off, 64));

  __shared__ float red[4];
  const int wid = tid >> 6;
  if ((tid & 63) == 0) red[wid] = vmax;
  __syncthreads();
  vmax = fmaxf(fmaxf(red[0], red[1]), fmaxf(red[2], red[3]));
  __syncthreads();

  float s = 0.f;
#pragma unroll
  for (int i = 0; i < 16; i++) {
    v[i] = expf(v[i] - vmax);
    s += v[i];
  }
#pragma unroll
  for (int off = 32; off > 0; off >>= 1) s += __shfl_xor(s, off, 64);
  if ((tid & 63) == 0) red[wid] = s;
  __syncthreads();
  s = (red[0] + red[1]) + (red[2] + red[3]);

  const float inv = 1.0f / s;
#pragma unroll
  for (int i = 0; i < 2; i++) {
    bf16x8 o;
#pragma unroll
    for (int j = 0; j < 8; j++) o[j] = (__bf16)(v[i * 8 + j] * inv);
    q[tid + i * 256] = o;
  }
}

// ---------------------------------------------------------------------------
// Reduce bf16 split-K partials (8 slices of 262144 elems per batch, batch
// stride 2097152) -> bf16 Mb. One thread = 8 output elems.
// ---------------------------------------------------------------------------
__global__ __launch_bounds__(256) void reduce_partials8b(
    const __bf16* __restrict__ P, __bf16* __restrict__ out) {
  const long i = ((long)blockIdx.x * 256 + threadIdx.x) * 8;  // < 2M
  const int b = (int)(i >> 18);
  const long il = i & 262143;
  const __bf16* p = P + (long)b * 2097152 + il;
  float s[8] = {};
#pragma unroll
  for (int sl = 0; sl < 8; sl++) {
    bf16x8 t = *(const bf16x8*)&p[(long)sl * 262144];
#pragma unroll
    for (int j = 0; j < 8; j++) s[j] += (float)t[j];
  }
  bf16x8 o;
#pragma unroll
  for (int j = 0; j < 8; j++) o[j] = (__bf16)s[j];
  *(bf16x8*)&out[i] = o;
}

// ---------------------------------------------------------------------------
// z<8:  x (fp32 [C,HW] batch z) -> xb (bf16 same layout) + xT (bf16 [HW,C]).
// z==8: weight/bias conversion (wB,wV -> wBVb stacked; wA -> wAb; bBV pack).
// v2 (G13): float4 global loads, bf16x4 global stores on BOTH outputs.
// Old version did 4 B/lane loads and 2 B/lane xb stores (1/8 coalescing).
// ---------------------------------------------------------------------------
__global__ __launch_bounds__(256) void convert_all(
    const float* __restrict__ x, __bf16* __restrict__ xb,
    __bf16* __restrict__ xT, const float* __restrict__ wA,
    const float* __restrict__ wB, const float* __restrict__ wV,
    const float* __restrict__ bB, const float* __restrict__ bV,
    __bf16* __restrict__ wAb, __bf16* __restrict__ wBVb,
    float* __restrict__ bBV) {
  if (blockIdx.z == 8) {
    const int t = blockIdx.y * 64 + blockIdx.x;  // 0..511
    const int grp = t >> 7;                      // 128 blocks per matrix
    const int r = t & 127;
    if (grp == 3) {
      if (r == 0) {
#pragma unroll
        for (int j = 0; j < 4; j++) {
          const int i = threadIdx.x * 4 + j;
          bBV[i] = (i < 512) ? bB[i] : bV[i - 512];
        }
      }
      return;
    }
    const float* in = grp == 0 ? wB : (grp == 1 ? wV : wA);
    __bf16* o = grp == 0 ? wBVb : (grp == 1 ? wBVb + 262144 : wAb);
    const long base = (long)r * 2048 + threadIdx.x * 8;  // 2048 elems/block
    float4 v0 = *(const float4*)&in[base];
    float4 v1 = *(const float4*)&in[base + 4];
    bf16x8 ob;
    ob[0] = (__bf16)v0.x; ob[1] = (__bf16)v0.y; ob[2] = (__bf16)v0.z;
    ob[3] = (__bf16)v0.w; ob[4] = (__bf16)v1.x; ob[5] = (__bf16)v1.y;
    ob[6] = (__bf16)v1.z; ob[7] = (__bf16)v1.w;
    *(bf16x8*)&o[base] = ob;
    return;
  }

  __shared__ __bf16 t[64][72];
  const int j0 = blockIdx.x * 64;   // hw tile
  const int c0 = blockIdx.y * 64;   // c tile
  const long bofs = (long)blockIdx.z * CC * HWN;
  const int cl = threadIdx.x & 15;  // 4-float column group
  const int rw = threadIdx.x >> 4;  // 0..15

#pragma unroll
  for (int p = 0; p < 4; p++) {
    const int i = p * 16 + rw;      // row in tile (c-dim)
    const float4 v =
        *(const float4*)&x[bofs + (long)(c0 + i) * HWN + j0 + cl * 4];
    bf16x4 ob;
    ob[0] = (__bf16)v.x; ob[1] = (__bf16)v.y;
    ob[2] = (__bf16)v.z; ob[3] = (__bf16)v.w;
    *(bf16x4*)&xb[bofs + (long)(c0 + i) * HWN + j0 + cl * 4] = ob;
    t[cl * 4 + 0][i] = ob[0];
    t[cl * 4 + 1][i] = ob[1];
    t[cl * 4 + 2][i] = ob[2];
    t[cl * 4 + 3][i] = ob[3];
  }
  __syncthreads();
#pragma unroll
  for (int p = 0; p < 4; p++) {
    const int jj = p * 16 + rw;     // row in xT tile (hw-dim)
    bf16x4 o;
    o[0] = t[jj][cl * 4 + 0];
    o[1] = t[jj][cl * 4 + 1];
    o[2] = t[jj][cl * 4 + 2];
    o[3] = t[jj][cl * 4 + 3];
    *(bf16x4*)&xT[bofs + (long)(j0 + jj) * CC + c0 + cl * 4] = o;
  }
}

// bf16 transpose: out[b*sOut + j*CC + c] = in[b*sIn + c*ldIn + j]
__global__ __launch_bounds__(256) void transpose_bf16_s(
    const __bf16* __restrict__ in, __bf16* __restrict__ out, int ldIn,
    long sIn, long sOut) {
  __shared__ __bf16 t[64][66];
  const int j0 = blockIdx.x * 64;
  const int c0 = blockIdx.y * 64;
  const int j = threadIdx.x & 63;
  const int g = threadIdx.x >> 6;

#pragma unroll
  for (int r = 0; r < 16; r++) {
    const int i = r * 4 + g;
    t[j][i] = in[(long)blockIdx.z * sIn + (long)(c0 + i) * ldIn + j0 + j];
  }
  __syncthreads();
#pragma unroll
  for (int r = 0; r < 16; r++) {
    const int jj = r * 4 + g;
    out[(long)blockIdx.z * sOut + (long)(j0 + jj) * CC + c0 + j] = t[jj][j];
  }
}

// ---------------------------------------------------------------------------
// Plan:
//  0. convert_all: x->xb,xT; weights->bf16 (stacked wBV); biases packed
//  1. logits = wBV·x + bBV  (M=1024)  [gemm256]      -> d_out bf16 [B,1024,HW]
//  2. softmax_dual: B-rows -> bm (ws), V-rows -> in place (av)
//  3. transpose av -> avT into xT region (xT dead)
//  4. M partials split-K=8 (A=bm,B=xb) [gemm256]     -> d_out bf16 (32 MiB)
//  5. reduce -> Mb bf16
//  6. gdT = (wA·M^T + bA)/HW (A=wAb,B=Mb) [gemm128]  -> gdT bf16
//  7. out = gdT·avT          (A=gdT,B=xT) [gemm256]  -> d_out fp32 (full 64MB)
// ---------------------------------------------------------------------------
extern "C" void kernel_launch(void* const* d_in, const int* in_sizes, int n_in,
                              void* d_out, int out_size, void* d_ws,
                              size_t ws_size, hipStream_t stream) {
  const float* x  = (const float*)d_in[0];
  const float* wA = (const float*)d_in[1];
  const float* bA = (const float*)d_in[2];
  const float* wB = (const float*)d_in[3];
  const float* bB = (const float*)d_in[4];
  const float* wV = (const float*)d_in[5];
  const float* bV = (const float*)d_in[6];
  float* out = (float*)d_out;

  const size_t nBCHW = (size_t)BB * CC * HWN;   // 16M
  const size_t nBCC  = (size_t)BB * CC * CC;    // 2M
  __bf16* xb   = (__bf16*)d_ws;          // [B,C,HW]
  __bf16* xT   = xb + nBCHW;             // [B,HW,C]; later avT
  __bf16* bm   = xT + nBCHW;             // [B,C,HW]
  __bf16* Mb   = bm + nBCHW;             // [B,C,C]
  __bf16* gdT  = Mb + nBCC;              // [B,C,C]
  __bf16* wBVb = gdT + nBCC;             // [1024,512]
  __bf16* wAb  = wBVb + (size_t)1024 * CC;
  float*  bBV  = (float*)(wAb + (size_t)CC * CC);  // [1024]

  const long sBC_HW = (long)CC * HWN;    // 2097152
  const long sCC = (long)CC * CC;        // 262144

  convert_all<<<dim3(HWN / 64, CC / 64, BB + 1), 256, 0, stream>>>(
      x, xb, xT, wA, wB, wV, bB, bV, wAb, wBVb, bBV);

  __bf16* logits = (__bf16*)d_out;       // [B,1024,HW] bf16 == 64 MiB

  // 1. merged logits GEMM (M=1024): rows 0-511 B-logits, 512-1023 V-logits
  gemm256_mfma_bt<1, __bf16>
      <<<dim3(HWN / 256, 1024 / 256, BB), 512, 0, stream>>>(
          wBVb, xT, bBV, logits, 1024, HWN, CC, 0, sBC_HW, (long)1024 * HWN,
          1.0f, 1, 0);
  // 2. dual softmax
  softmax_dual_bf16<<<dim3(BB * 1024), 256, 0, stream>>>(logits, bm);
  // 3. avT (av rows live at logits + b*4194304 + 2097152 + c*4096)
  transpose_bf16_s<<<dim3(HWN / 64, CC / 64, BB), 256, 0, stream>>>(
      logits + 2097152, xT, HWN, (long)1024 * HWN, (long)HWN * CC);
  // 4. M split-K=8 partials -> d_out as bf16: batch 2097152, slice 262144
  gemm256_mfma_bt<0, __bf16><<<dim3(CC / 256, CC / 256, BB * 8), 512, 0,
                               stream>>>(bm, xb, nullptr, (__bf16*)out, CC,
                                         CC, HWN, sBC_HW, sBC_HW,
                                         (long)2097152, 1.0f, 8,
                                         (long)262144);
  // 5. reduce -> Mb
  reduce_partials8b<<<dim3(1024), 256, 0, stream>>>((const __bf16*)out, Mb);
  // 6. gdT = (wA @ M^T + bA)/HW  (small grid -> 128^2 kernel)
  gemm_mfma_bt<1, __bf16><<<dim3(CC / 128, CC / 128, BB), 256, 0, stream>>>(
      wAb, Mb, bA, gdT, CC, CC, CC, 0, sCC, sCC, 1.0f / (float)HWN, 1, 0);
  // 7. out = gdT @ avT -> d_out (fp32, overwrites everything)
  gemm256_mfma_bt<0, float>
      <<<dim3(HWN / 256, CC / 256, BB), 512, 0, stream>>>(
          gdT, xT, nullptr, out, CC, HWN, CC, sCC, sBC_HW, sBC_HW, 1.0f, 1,
          0);
}

// Round 6
// 278.175 us; speedup vs baseline: 3.0775x; 1.0529x over previous
//
#include <hip/hip_runtime.h>
#include <math.h>

#define BB 8
#define CC 512
#define HWN 4096

typedef __bf16 bf16x8 __attribute__((ext_vector_type(8)));
typedef __bf16 bf16x4 __attribute__((ext_vector_type(4)));
typedef float f32x4 __attribute__((ext_vector_type(4)));

#define GLOBAL_AS __attribute__((address_space(1)))
#define LDS_AS __attribute__((address_space(3)))

static __device__ __forceinline__ void async_copy16(const void* g, void* l) {
  __builtin_amdgcn_global_load_lds((const GLOBAL_AS unsigned int*)g,
                                   (LDS_AS unsigned int*)l, 16, 0, 0);
}

// ---------------------------------------------------------------------------
// v7: 256x256 8-wave GEMM, m201-faithful phase ordering. BT form:
//   C[m,n] = alpha*(sum_k A[m,k]*B[n,k] + bias[m]?)
// R5 post-mortem: ALL prior versions (545-625 TF) issued stage() BEFORE the
// fragment ds_reads. The ds_reads alias in-flight global_load_lds writes
// (same __shared__ array, dynamic buf index), so the compiler conservatively
// drains VMEM before the read cluster -- waiting on a load issued ~20 instrs
// earlier = full HBM latency exposed EVERY tile, making counted-vmcnt moot.
// m201's template reads FIRST in each phase (its reads-first 8-phase hits
// 1167 TF unswizzled vs ~680 for the stage-first 2-phase recipe).
// Phase structure per K-tile t (BK=32, buf = t&3, 4 bufs = 128 KiB):
//   P0: ds_read bfr[4]+af[4] | SB0 | stageA(t+2) | barrier | SB0
//       setprio(1) 16 MFMA (m0-3) setprio(0) | barrier | SB0
//   P1: ds_read af2[4]       | SB0 | stageB(t+2) | vmcnt(4|0) | barrier | SB0
//       setprio(1) 16 MFMA (m4-7) setprio(0) | barrier | SB0
// vmcnt ledger (2 instrs per stage call): at P1's wait, in flight =
// A(t+1)[t-1.P0] B(t+1)[t-1.P1] A(t+2)[t.P0] B(t+2)[t.P1] = 8; vmcnt(4)
// retires through B(t+1) (issue order, m135) -> tile t+1 resident; barrier
// promotes per-wave -> all-waves. Youngest waited load is 1 full tile old
// (~600-1000cy) -> latency covered. Tail: t==NT-2 -> vmcnt(0) (4 left),
// t==NT-1 -> vmcnt(0) free. Race: stage(t+2)->buf[(t+2)&3] last read at
// t-2, >=2 closed barriers earlier; every wave's reads drain (lgkm) before
// its MFMAs before each closing barrier.
// Split-K: grid.z = batch*ksl + slice; slice output at Cg + slice*sSlice.
// ---------------------------------------------------------------------------
template <int BIASMODE, typename OUT_T>
__global__ __launch_bounds__(512, 2) void gemm256_mfma_bt(
    const __bf16* __restrict__ Ag, const __bf16* __restrict__ Bg,
    const float* __restrict__ bias, OUT_T* __restrict__ Cg,
    int M, int N, int K, long sA, long sB, long sC, float alpha,
    int ksl, long sSlice) {
  __shared__ __align__(16) __bf16 As[4][256][32];  // 64 KiB
  __shared__ __align__(16) __bf16 Bs[4][256][32];  // 64 KiB

  const int tid = threadIdx.x;
  const int n0 = blockIdx.x * 256;
  const int m0 = blockIdx.y * 256;
  const int bz = blockIdx.z;
  const int batch = bz / ksl;
  const int slice = bz - batch * ksl;
  const int kLen = K / ksl;
  const int kBeg = slice * kLen;
  const int NT = kLen >> 5;  // K-tiles of 32 (all call sites: NT == 16)
  Ag += (long)batch * sA;
  Bg += (long)batch * sB;
  Cg += (long)batch * sC + (long)slice * sSlice;

  const int lane = tid & 63;
  const int w = tid >> 6;   // 0..7
  const int wr = w >> 2;    // m-half 0..1
  const int wn = w & 3;     // n-quarter 0..3
  const int l15 = lane & 15, quad = lane >> 4;

  // Staging map: thread tid covers LDS bytes [tid*16,+16) of each 8KB step;
  // step s covers rows s*128..s*128+127. row = s*128 + (tid>>2), seg tid&3.
  // LDS dest = wave-uniform base + lane*16 (global_load_lds requirement).
  const __bf16* Arow = Ag + (long)(m0 + (tid >> 2)) * K + (tid & 3) * 8;
  const __bf16* Brow = Bg + (long)(n0 + (tid >> 2)) * K + (tid & 3) * 8;

  f32x4 acc[8][4] = {};

  auto stageA = [&](int t) {
    const int b = t & 3;
    const int kk = kBeg + t * 32;
#pragma unroll
    for (int s = 0; s < 2; s++)
      async_copy16(Arow + (long)s * 128 * K + kk,
                   (char*)&As[b][0][0] + s * 8192 + tid * 16);
  };
  auto stageB = [&](int t) {
    const int b = t & 3;
    const int kk = kBeg + t * 32;
#pragma unroll
    for (int s = 0; s < 2; s++)
      async_copy16(Brow + (long)s * 128 * K + kk,
                   (char*)&Bs[b][0][0] + s * 8192 + tid * 16);
  };

  // prologue: tiles 0,1 issued (8 instrs). Retire tile 0 (keep tile 1 in
  // flight), then all-waves barrier.
  stageA(0); stageB(0);
  stageA(1); stageB(1);
  asm volatile("s_waitcnt vmcnt(4)" ::: "memory");
  __builtin_amdgcn_s_barrier();
  __builtin_amdgcn_sched_barrier(0);

  for (int t = 0; t < NT; t++) {
    const int b = t & 3;
    const __bf16(*Asb)[32] = As[b];
    const __bf16(*Bsb)[32] = Bs[b];

    // ---- P0: reads FIRST, then stage issue ----
    bf16x8 bfr[4], af[4];
#pragma unroll
    for (int nj = 0; nj < 4; nj++)
      bfr[nj] = *(const bf16x8*)&Bsb[wn * 64 + nj * 16 + l15][quad * 8];
#pragma unroll
    for (int mi = 0; mi < 4; mi++)
      af[mi] = *(const bf16x8*)&Asb[wr * 128 + mi * 16 + l15][quad * 8];
    __builtin_amdgcn_sched_barrier(0);   // reads stay above the stage issue
    if (t + 2 < NT) stageA(t + 2);
    __builtin_amdgcn_s_barrier();
    __builtin_amdgcn_sched_barrier(0);
    __builtin_amdgcn_s_setprio(1);
#pragma unroll
    for (int mi = 0; mi < 4; mi++)
#pragma unroll
      for (int nj = 0; nj < 4; nj++)
        acc[mi][nj] = __builtin_amdgcn_mfma_f32_16x16x32_bf16(
            af[mi], bfr[nj], acc[mi][nj], 0, 0, 0);
    __builtin_amdgcn_s_setprio(0);
    __builtin_amdgcn_s_barrier();
    __builtin_amdgcn_sched_barrier(0);

    // ---- P1: reads FIRST, stage issue, boundary vmcnt ----
    bf16x8 af2[4];
#pragma unroll
    for (int mi = 0; mi < 4; mi++)
      af2[mi] = *(const bf16x8*)&Asb[wr * 128 + 64 + mi * 16 + l15][quad * 8];
    __builtin_amdgcn_sched_barrier(0);
    if (t + 2 < NT) stageB(t + 2);
    // Boundary: tile t+1 must be resident before anyone reads it next iter.
    // In flight: A(t+1),B(t+1),A(t+2),B(t+2) = 8 instrs; vmcnt(4) retires
    // through B(t+1). Youngest waited load issued 1 full tile ago.
    if (t < NT - 2)
      asm volatile("s_waitcnt vmcnt(4)" ::: "memory");
    else
      asm volatile("s_waitcnt vmcnt(0)" ::: "memory");
    __builtin_amdgcn_s_barrier();
    __builtin_amdgcn_sched_barrier(0);
    __builtin_amdgcn_s_setprio(1);
#pragma unroll
    for (int mi = 0; mi < 4; mi++)
#pragma unroll
      for (int nj = 0; nj < 4; nj++)
        acc[mi + 4][nj] = __builtin_amdgcn_mfma_f32_16x16x32_bf16(
            af2[mi], bfr[nj], acc[mi + 4][nj], 0, 0, 0);
    __builtin_amdgcn_s_setprio(0);
    __builtin_amdgcn_s_barrier();
    __builtin_amdgcn_sched_barrier(0);
  }

#pragma unroll
  for (int mi = 0; mi < 8; mi++) {
#pragma unroll
    for (int nj = 0; nj < 4; nj++) {
#pragma unroll
      for (int r = 0; r < 4; r++) {
        const int m = m0 + wr * 128 + mi * 16 + quad * 4 + r;
        const int n = n0 + wn * 64 + nj * 16 + l15;
        float v = acc[mi][nj][r];
        if (BIASMODE == 1) v += bias[m];
        Cg[(long)m * N + n] = (OUT_T)(v * alpha);
      }
    }
  }
}

// ---------------------------------------------------------------------------
// 128^2 4-wave GEMM — step 6 only (128 blocks). v7: same reads-first fix.
// Ledger: prologue stages 0,1,2 (12 instrs). Top of tile t: vmcnt(8)
// retires tile t's 4 (oldest). Reads then stage(t+3) -> back to 12.
// ---------------------------------------------------------------------------
template <int BIASMODE, typename OUT_T>
__global__ __launch_bounds__(256) void gemm_mfma_bt(
    const __bf16* __restrict__ Ag, const __bf16* __restrict__ Bg,
    const float* __restrict__ bias, OUT_T* __restrict__ Cg,
    int M, int N, int K, long sA, long sB, long sC, float alpha,
    int ksl, long sSlice) {
  __shared__ __align__(16) __bf16 As[4][128][32];
  __shared__ __align__(16) __bf16 Bs[4][128][32];

  const int tid = threadIdx.x;
  const int n0 = blockIdx.x * 128;
  const int m0 = blockIdx.y * 128;
  const int bz = blockIdx.z;
  const int batch = bz / ksl;
  const int slice = bz - batch * ksl;
  const int kLen = K / ksl;
  const int kBeg = slice * kLen;
  const int NT = kLen >> 5;
  Ag += (long)batch * sA;
  Bg += (long)batch * sB;
  Cg += (long)batch * sC + (long)slice * sSlice;

  const int lane = tid & 63;
  const int w = tid >> 6;
  const int wr = w >> 1, wc = w & 1;
  const int l15 = lane & 15, quad = lane >> 4;

  const int srow = tid >> 2;
  const int scol = (tid & 3) * 8;
  const __bf16* Arow = Ag + (long)(m0 + srow) * K + scol;
  const __bf16* Brow = Bg + (long)(n0 + srow) * K + scol;

  f32x4 acc[4][4] = {};

  auto stageT = [&](int t) {
    const int b = t & 3;
    const int kk = kBeg + t * 32;
#pragma unroll
    for (int s = 0; s < 2; s++) {
      async_copy16(Arow + (long)s * 64 * K + kk,
                   (char*)&As[b][0][0] + s * 4096 + tid * 16);
      async_copy16(Brow + (long)s * 64 * K + kk,
                   (char*)&Bs[b][0][0] + s * 4096 + tid * 16);
    }
  };

  stageT(0);
  if (NT > 1) stageT(1);
  if (NT > 2) stageT(2);

  for (int t = 0; t < NT; t++) {
    if (t < NT - 2)
      asm volatile("s_waitcnt vmcnt(8)" ::: "memory");
    else if (t == NT - 2)
      asm volatile("s_waitcnt vmcnt(4)" ::: "memory");
    else
      asm volatile("s_waitcnt vmcnt(0)" ::: "memory");
    __builtin_amdgcn_s_barrier();
    __builtin_amdgcn_sched_barrier(0);

    const int b = t & 3;
    bf16x8 af[4], bfr[4];
#pragma unroll
    for (int u = 0; u < 4; u++) {
      af[u]  = *(const bf16x8*)&As[b][wr * 64 + u * 16 + l15][quad * 8];
      bfr[u] = *(const bf16x8*)&Bs[b][wc * 64 + u * 16 + l15][quad * 8];
    }
    __builtin_amdgcn_sched_barrier(0);  // reads stay above the stage issue
    if (t + 3 < NT) stageT(t + 3);

    __builtin_amdgcn_s_setprio(1);
#pragma unroll
    for (int ti = 0; ti < 4; ti++)
#pragma unroll
      for (int tj = 0; tj < 4; tj++)
        acc[ti][tj] = __builtin_amdgcn_mfma_f32_16x16x32_bf16(
            af[ti], bfr[tj], acc[ti][tj], 0, 0, 0);
    __builtin_amdgcn_s_setprio(0);
  }

#pragma unroll
  for (int ti = 0; ti < 4; ti++) {
#pragma unroll
    for (int tj = 0; tj < 4; tj++) {
#pragma unroll
      for (int r = 0; r < 4; r++) {
        const int m = m0 + wr * 64 + ti * 16 + quad * 4 + r;
        const int n = n0 + wc * 64 + tj * 16 + l15;
        float v = acc[ti][tj][r];
        if (BIASMODE == 1) v += bias[m];
        Cg[(long)m * N + n] = (OUT_T)(v * alpha);
      }
    }
  }
}

// ---------------------------------------------------------------------------
// Dual softmax over bf16 logit rows [B,1024,HWN] in d_out.
// Row c<512 (B-logits): write normalized bf16 row to bm[b,c,:].
// Row c>=512 (V-logits): write back in place (av).
// ---------------------------------------------------------------------------
__global__ __launch_bounds__(256) void softmax_dual_bf16(
    __bf16* __restrict__ logits, __bf16* __restrict__ bm) {
  const int row = blockIdx.x;                 // 0..8191
  const int b = row >> 10, c = row & 1023;
  __bf16* src = logits + ((long)b * 1024 + c) * HWN;
  __bf16* dst = (c < 512) ? (bm + ((long)b * 512 + c) * HWN) : src;
  const int tid = threadIdx.x;

  const bf16x8* p = reinterpret_cast<const bf16x8*>(src);
  bf16x8* q = reinterpret_cast<bf16x8*>(dst);

  float v[16];
  float vmax = -3.0e38f;
#pragma unroll
  for (int i = 0; i < 2; i++) {
    bf16x8 t = p[tid + i * 256];
#pragma unroll
    for (int j = 0; j < 8; j++) {
      v[i * 8 + j] = (float)t[j];
      vmax = fmaxf(vmax, v[i * 8 + j]);
    }
  }
#pragma unroll
  for (int off = 32; off > 0; off >>= 1)
    vmax = fmaxf(vmax, __shfl_xor(vmax, off, 64));

  __shared__ float red[4];
  const int wid = tid >> 6;
  if ((tid & 63) == 0) red[wid] = vmax;
  __syncthreads();
  vmax = fmaxf(fmaxf(red[0], red[1]), fmaxf(red[2], red[3]));
  __syncthreads();

  float s = 0.f;
#pragma unroll
  for (int i = 0; i < 16; i++) {
    v[i] = expf(v[i] - vmax);
    s += v[i];
  }
#pragma unroll
  for (int off = 32; off > 0; off >>= 1) s += __shfl_xor(s, off, 64);
  if ((tid & 63) == 0) red[wid] = s;
  __syncthreads();
  s = (red[0] + red[1]) + (red[2] + red[3]);

  const float inv = 1.0f / s;
#pragma unroll
  for (int i = 0; i < 2; i++) {
    bf16x8 o;
#pragma unroll
    for (int j = 0; j < 8; j++) o[j] = (__bf16)(v[i * 8 + j] * inv);
    q[tid + i * 256] = o;
  }
}

// ---------------------------------------------------------------------------
// Reduce bf16 split-K partials (8 slices of 262144 elems per batch, batch
// stride 2097152) -> bf16 Mb. One thread = 8 output elems.
// ---------------------------------------------------------------------------
__global__ __launch_bounds__(256) void reduce_partials8b(
    const __bf16* __restrict__ P, __bf16* __restrict__ out) {
  const long i = ((long)blockIdx.x * 256 + threadIdx.x) * 8;  // < 2M
  const int b = (int)(i >> 18);
  const long il = i & 262143;
  const __bf16* p = P + (long)b * 2097152 + il;
  float s[8] = {};
#pragma unroll
  for (int sl = 0; sl < 8; sl++) {
    bf16x8 t = *(const bf16x8*)&p[(long)sl * 262144];
#pragma unroll
    for (int j = 0; j < 8; j++) s[j] += (float)t[j];
  }
  bf16x8 o;
#pragma unroll
  for (int j = 0; j < 8; j++) o[j] = (__bf16)s[j];
  *(bf16x8*)&out[i] = o;
}

// ---------------------------------------------------------------------------
// z<8:  x (fp32 [C,HW] batch z) -> xb (bf16 same layout) + xT (bf16 [HW,C]).
// z==8: weight/bias conversion (wB,wV -> wBVb stacked; wA -> wAb; bBV pack).
// float4 global loads, bf16x4 global stores on BOTH outputs (G13).
// ---------------------------------------------------------------------------
__global__ __launch_bounds__(256) void convert_all(
    const float* __restrict__ x, __bf16* __restrict__ xb,
    __bf16* __restrict__ xT, const float* __restrict__ wA,
    const float* __restrict__ wB, const float* __restrict__ wV,
    const float* __restrict__ bB, const float* __restrict__ bV,
    __bf16* __restrict__ wAb, __bf16* __restrict__ wBVb,
    float* __restrict__ bBV) {
  if (blockIdx.z == 8) {
    const int t = blockIdx.y * 64 + blockIdx.x;  // 0..511
    const int grp = t >> 7;                      // 128 blocks per matrix
    const int r = t & 127;
    if (grp == 3) {
      if (r == 0) {
#pragma unroll
        for (int j = 0; j < 4; j++) {
          const int i = threadIdx.x * 4 + j;
          bBV[i] = (i < 512) ? bB[i] : bV[i - 512];
        }
      }
      return;
    }
    const float* in = grp == 0 ? wB : (grp == 1 ? wV : wA);
    __bf16* o = grp == 0 ? wBVb : (grp == 1 ? wBVb + 262144 : wAb);
    const long base = (long)r * 2048 + threadIdx.x * 8;  // 2048 elems/block
    float4 v0 = *(const float4*)&in[base];
    float4 v1 = *(const float4*)&in[base + 4];
    bf16x8 ob;
    ob[0] = (__bf16)v0.x; ob[1] = (__bf16)v0.y; ob[2] = (__bf16)v0.z;
    ob[3] = (__bf16)v0.w; ob[4] = (__bf16)v1.x; ob[5] = (__bf16)v1.y;
    ob[6] = (__bf16)v1.z; ob[7] = (__bf16)v1.w;
    *(bf16x8*)&o[base] = ob;
    return;
  }

  __shared__ __bf16 t[64][72];
  const int j0 = blockIdx.x * 64;   // hw tile
  const int c0 = blockIdx.y * 64;   // c tile
  const long bofs = (long)blockIdx.z * CC * HWN;
  const int cl = threadIdx.x & 15;  // 4-float column group
  const int rw = threadIdx.x >> 4;  // 0..15

#pragma unroll
  for (int p = 0; p < 4; p++) {
    const int i = p * 16 + rw;      // row in tile (c-dim)
    const float4 v =
        *(const float4*)&x[bofs + (long)(c0 + i) * HWN + j0 + cl * 4];
    bf16x4 ob;
    ob[0] = (__bf16)v.x; ob[1] = (__bf16)v.y;
    ob[2] = (__bf16)v.z; ob[3] = (__bf16)v.w;
    *(bf16x4*)&xb[bofs + (long)(c0 + i) * HWN + j0 + cl * 4] = ob;
    t[cl * 4 + 0][i] = ob[0];
    t[cl * 4 + 1][i] = ob[1];
    t[cl * 4 + 2][i] = ob[2];
    t[cl * 4 + 3][i] = ob[3];
  }
  __syncthreads();
#pragma unroll
  for (int p = 0; p < 4; p++) {
    const int jj = p * 16 + rw;     // row in xT tile (hw-dim)
    bf16x4 o;
    o[0] = t[jj][cl * 4 + 0];
    o[1] = t[jj][cl * 4 + 1];
    o[2] = t[jj][cl * 4 + 2];
    o[3] = t[jj][cl * 4 + 3];
    *(bf16x4*)&xT[bofs + (long)(j0 + jj) * CC + c0 + cl * 4] = o;
  }
}

// bf16 transpose: out[b*sOut + j*CC + c] = in[b*sIn + c*ldIn + j]
__global__ __launch_bounds__(256) void transpose_bf16_s(
    const __bf16* __restrict__ in, __bf16* __restrict__ out, int ldIn,
    long sIn, long sOut) {
  __shared__ __bf16 t[64][66];
  const int j0 = blockIdx.x * 64;
  const int c0 = blockIdx.y * 64;
  const int j = threadIdx.x & 63;
  const int g = threadIdx.x >> 6;

#pragma unroll
  for (int r = 0; r < 16; r++) {
    const int i = r * 4 + g;
    t[j][i] = in[(long)blockIdx.z * sIn + (long)(c0 + i) * ldIn + j0 + j];
  }
  __syncthreads();
#pragma unroll
  for (int r = 0; r < 16; r++) {
    const int jj = r * 4 + g;
    out[(long)blockIdx.z * sOut + (long)(j0 + jj) * CC + c0 + j] = t[jj][j];
  }
}

// ---------------------------------------------------------------------------
// Plan:
//  0. convert_all: x->xb,xT; weights->bf16 (stacked wBV); biases packed
//  1. logits = wBV·x + bBV  (M=1024)  [gemm256]      -> d_out bf16 [B,1024,HW]
//  2. softmax_dual: B-rows -> bm (ws), V-rows -> in place (av)
//  3. transpose av -> avT into xT region (xT dead)
//  4. M partials split-K=8 (A=bm,B=xb) [gemm256]     -> d_out bf16 (32 MiB)
//  5. reduce -> Mb bf16
//  6. gdT = (wA·M^T + bA)/HW (A=wAb,B=Mb) [gemm128]  -> gdT bf16
//  7. out = gdT·avT          (A=gdT,B=xT) [gemm256]  -> d_out fp32 (full 64MB)
// ---------------------------------------------------------------------------
extern "C" void kernel_launch(void* const* d_in, const int* in_sizes, int n_in,
                              void* d_out, int out_size, void* d_ws,
                              size_t ws_size, hipStream_t stream) {
  const float* x  = (const float*)d_in[0];
  const float* wA = (const float*)d_in[1];
  const float* bA = (const float*)d_in[2];
  const float* wB = (const float*)d_in[3];
  const float* bB = (const float*)d_in[4];
  const float* wV = (const float*)d_in[5];
  const float* bV = (const float*)d_in[6];
  float* out = (float*)d_out;

  const size_t nBCHW = (size_t)BB * CC * HWN;   // 16M
  const size_t nBCC  = (size_t)BB * CC * CC;    // 2M
  __bf16* xb   = (__bf16*)d_ws;          // [B,C,HW]
  __bf16* xT   = xb + nBCHW;             // [B,HW,C]; later avT
  __bf16* bm   = xT + nBCHW;             // [B,C,HW]
  __bf16* Mb   = bm + nBCHW;             // [B,C,C]
  __bf16* gdT  = Mb + nBCC;              // [B,C,C]
  __bf16* wBVb = gdT + nBCC;             // [1024,512]
  __bf16* wAb  = wBVb + (size_t)1024 * CC;
  float*  bBV  = (float*)(wAb + (size_t)CC * CC);  // [1024]

  const long sBC_HW = (long)CC * HWN;    // 2097152
  const long sCC = (long)CC * CC;        // 262144

  convert_all<<<dim3(HWN / 64, CC / 64, BB + 1), 256, 0, stream>>>(
      x, xb, xT, wA, wB, wV, bB, bV, wAb, wBVb, bBV);

  __bf16* logits = (__bf16*)d_out;       // [B,1024,HW] bf16 == 64 MiB

  // 1. merged logits GEMM (M=1024): rows 0-511 B-logits, 512-1023 V-logits
  gemm256_mfma_bt<1, __bf16>
      <<<dim3(HWN / 256, 1024 / 256, BB), 512, 0, stream>>>(
          wBVb, xT, bBV, logits, 1024, HWN, CC, 0, sBC_HW, (long)1024 * HWN,
          1.0f, 1, 0);
  // 2. dual softmax
  softmax_dual_bf16<<<dim3(BB * 1024), 256, 0, stream>>>(logits, bm);
  // 3. avT (av rows live at logits + b*4194304 + 2097152 + c*4096)
  transpose_bf16_s<<<dim3(HWN / 64, CC / 64, BB), 256, 0, stream>>>(
      logits + 2097152, xT, HWN, (long)1024 * HWN, (long)HWN * CC);
  // 4. M split-K=8 partials -> d_out as bf16: batch 2097152, slice 262144
  gemm256_mfma_bt<0, __bf16><<<dim3(CC / 256, CC / 256, BB * 8), 512, 0,
                               stream>>>(bm, xb, nullptr, (__bf16*)out, CC,
                                         CC, HWN, sBC_HW, sBC_HW,
                                         (long)2097152, 1.0f, 8,
                                         (long)262144);
  // 5. reduce -> Mb
  reduce_partials8b<<<dim3(1024), 256, 0, stream>>>((const __bf16*)out, Mb);
  // 6. gdT = (wA @ M^T + bA)/HW  (small grid -> 128^2 kernel)
  gemm_mfma_bt<1, __bf16><<<dim3(CC / 128, CC / 128, BB), 256, 0, stream>>>(
      wAb, Mb, bA, gdT, CC, CC, CC, 0, sCC, sCC, 1.0f / (float)HWN, 1, 0);
  // 7. out = gdT @ avT -> d_out (fp32, overwrites everything)
  gemm256_mfma_bt<0, float>
      <<<dim3(HWN / 256, CC / 256, BB), 512, 0, stream>>>(
          gdT, xT, nullptr, out, CC, HWN, CC, sCC, sBC_HW, sBC_HW, 1.0f, 1,
          0);
}

// Round 7
// 272.414 us; speedup vs baseline: 3.1426x; 1.0211x over previous
//
#include <hip/hip_runtime.h>
#include <math.h>

#define BB 8
#define CC 512
#define HWN 4096

typedef __bf16 bf16x8 __attribute__((ext_vector_type(8)));
typedef __bf16 bf16x4 __attribute__((ext_vector_type(4)));
typedef float f32x4 __attribute__((ext_vector_type(4)));

#define GLOBAL_AS __attribute__((address_space(1)))
#define LDS_AS __attribute__((address_space(3)))

static __device__ __forceinline__ void async_copy16(const void* g, void* l) {
  __builtin_amdgcn_global_load_lds((const GLOBAL_AS unsigned int*)g,
                                   (LDS_AS unsigned int*)l, 16, 0, 0);
}

// ---------------------------------------------------------------------------
// v8: 256x256 8-wave GEMM, FULLY UNROLLED K-loop (NT compile-time). BT form:
//   C[m,n] = alpha*(sum_k A[m,k]*B[n,k] + bias[m]?)
// R6 post-mortem: six schedule variants all pinned at 545-625 TF. Root-cause
// theory: the buffer index (t&3) was RUNTIME-dynamic in all of them. The
// compiler cannot prove ds_read As[t&3] disjoint from in-flight
// global_load_lds writes to As[(t+2)&3] (same object, dynamic offsets), so
// the AMDGPU waitcnt pass inserts its own conservative vmcnt(0) drain before
// every fragment-read cluster -- independent of my inline-asm waits (the
// pass doesn't parse asm strings). That drains the YOUNGEST stage (issued
// ~20 instrs earlier) every tile = full HBM latency exposed 16x, which is
// why every barrier/vmcnt permutation measured the same.
// Fix: NT=16 at every call site -> template NT + #pragma unroll -> b = t&3
// folds to a constant -> GEP alias analysis proves the read range (e.g.
// As[0..16KB)) disjoint from the staged range (As[48..64KB)) -> the pass
// emits COUNTED waits against the true dependency only (stages issued 2
// tiles ~ 2500cy earlier). Manual pre-barrier counted vmcnt retained: it is
// the cross-wave guarantee (each wave drains ITS OWN tile-t stages before
// the barrier; barrier promotes to all-waves). Unroll also constant-folds
// per-tile address math (VALUBusy showed ~700cy/tile of it).
// Skeleton = v7 (reads-first phases, 4 bufs, lead-2, setprio): per K-tile t
//   P0: ds_read bfr[4]+af[4] | SB0 | stageA(t+2) | barrier | SB0 | 16 MFMA
//       | barrier | SB0
//   P1: ds_read af2[4] | SB0 | stageB(t+2) | vmcnt(4|0) | barrier | SB0
//       | 16 MFMA | barrier | SB0
// vmcnt ledger (2 instrs/stage): at P1's wait in flight = A(t+1),B(t+1),
// A(t+2),B(t+2) = 8; vmcnt(4) retires through B(t+1) (issue order, m135) ->
// tile t+1 resident; youngest waited load is 1 full tile old. Tail:
// t==NT-2 -> vmcnt(0). Race: stage(t+2)->buf[(t+2)&3] last read at t-2,
// >=2 closed barriers earlier.
// Split-K: grid.z = batch*ksl + slice; slice output at Cg + slice*sSlice.
// ---------------------------------------------------------------------------
template <int BIASMODE, typename OUT_T, int NT>
__global__ __launch_bounds__(512, 2) void gemm256_mfma_bt(
    const __bf16* __restrict__ Ag, const __bf16* __restrict__ Bg,
    const float* __restrict__ bias, OUT_T* __restrict__ Cg,
    int M, int N, int K, long sA, long sB, long sC, float alpha,
    int ksl, long sSlice) {
  __shared__ __align__(16) __bf16 As[4][256][32];  // 64 KiB
  __shared__ __align__(16) __bf16 Bs[4][256][32];  // 64 KiB

  const int tid = threadIdx.x;
  const int n0 = blockIdx.x * 256;
  const int m0 = blockIdx.y * 256;
  const int bz = blockIdx.z;
  const int batch = bz / ksl;
  const int slice = bz - batch * ksl;
  const int kBeg = slice * (NT * 32);
  Ag += (long)batch * sA;
  Bg += (long)batch * sB;
  Cg += (long)batch * sC + (long)slice * sSlice;

  const int lane = tid & 63;
  const int w = tid >> 6;   // 0..7
  const int wr = w >> 2;    // m-half 0..1
  const int wn = w & 3;     // n-quarter 0..3
  const int l15 = lane & 15, quad = lane >> 4;

  // Staging map: thread tid covers LDS bytes [tid*16,+16) of each 8KB step;
  // step s covers rows s*128..s*128+127. row = s*128 + (tid>>2), seg tid&3.
  // LDS dest = wave-uniform base + lane*16 (global_load_lds requirement).
  const __bf16* Arow = Ag + (long)(m0 + (tid >> 2)) * K + (tid & 3) * 8;
  const __bf16* Brow = Bg + (long)(n0 + (tid >> 2)) * K + (tid & 3) * 8;

  f32x4 acc[8][4] = {};

  auto stageA = [&](int t) {
    const int b = t & 3;  // compile-time after unroll
    const int kk = kBeg + t * 32;
#pragma unroll
    for (int s = 0; s < 2; s++)
      async_copy16(Arow + (long)s * 128 * K + kk,
                   (char*)&As[b][0][0] + s * 8192 + tid * 16);
  };
  auto stageB = [&](int t) {
    const int b = t & 3;
    const int kk = kBeg + t * 32;
#pragma unroll
    for (int s = 0; s < 2; s++)
      async_copy16(Brow + (long)s * 128 * K + kk,
                   (char*)&Bs[b][0][0] + s * 8192 + tid * 16);
  };

  // prologue: tiles 0,1 issued (8 instrs). Retire tile 0 (keep tile 1 in
  // flight), then all-waves barrier.
  stageA(0); stageB(0);
  stageA(1); stageB(1);
  asm volatile("s_waitcnt vmcnt(4)" ::: "memory");
  __builtin_amdgcn_s_barrier();
  __builtin_amdgcn_sched_barrier(0);

#pragma unroll
  for (int t = 0; t < NT; t++) {
    const int b = t & 3;  // constant per unrolled iteration
    const __bf16(*Asb)[32] = As[b];
    const __bf16(*Bsb)[32] = Bs[b];

    // ---- P0: reads FIRST, then stage issue ----
    bf16x8 bfr[4], af[4];
#pragma unroll
    for (int nj = 0; nj < 4; nj++)
      bfr[nj] = *(const bf16x8*)&Bsb[wn * 64 + nj * 16 + l15][quad * 8];
#pragma unroll
    for (int mi = 0; mi < 4; mi++)
      af[mi] = *(const bf16x8*)&Asb[wr * 128 + mi * 16 + l15][quad * 8];
    __builtin_amdgcn_sched_barrier(0);   // reads stay above the stage issue
    if (t + 2 < NT) stageA(t + 2);
    __builtin_amdgcn_s_barrier();
    __builtin_amdgcn_sched_barrier(0);
    __builtin_amdgcn_s_setprio(1);
#pragma unroll
    for (int mi = 0; mi < 4; mi++)
#pragma unroll
      for (int nj = 0; nj < 4; nj++)
        acc[mi][nj] = __builtin_amdgcn_mfma_f32_16x16x32_bf16(
            af[mi], bfr[nj], acc[mi][nj], 0, 0, 0);
    __builtin_amdgcn_s_setprio(0);
    __builtin_amdgcn_s_barrier();
    __builtin_amdgcn_sched_barrier(0);

    // ---- P1: reads FIRST, stage issue, boundary vmcnt ----
    bf16x8 af2[4];
#pragma unroll
    for (int mi = 0; mi < 4; mi++)
      af2[mi] = *(const bf16x8*)&Asb[wr * 128 + 64 + mi * 16 + l15][quad * 8];
    __builtin_amdgcn_sched_barrier(0);
    if (t + 2 < NT) stageB(t + 2);
    // Boundary: tile t+1 must be resident before anyone reads it next iter.
    if (t < NT - 2)
      asm volatile("s_waitcnt vmcnt(4)" ::: "memory");
    else
      asm volatile("s_waitcnt vmcnt(0)" ::: "memory");
    __builtin_amdgcn_s_barrier();
    __builtin_amdgcn_sched_barrier(0);
    __builtin_amdgcn_s_setprio(1);
#pragma unroll
    for (int mi = 0; mi < 4; mi++)
#pragma unroll
      for (int nj = 0; nj < 4; nj++)
        acc[mi + 4][nj] = __builtin_amdgcn_mfma_f32_16x16x32_bf16(
            af2[mi], bfr[nj], acc[mi + 4][nj], 0, 0, 0);
    __builtin_amdgcn_s_setprio(0);
    __builtin_amdgcn_s_barrier();
    __builtin_amdgcn_sched_barrier(0);
  }

#pragma unroll
  for (int mi = 0; mi < 8; mi++) {
#pragma unroll
    for (int nj = 0; nj < 4; nj++) {
#pragma unroll
      for (int r = 0; r < 4; r++) {
        const int m = m0 + wr * 128 + mi * 16 + quad * 4 + r;
        const int n = n0 + wn * 64 + nj * 16 + l15;
        float v = acc[mi][nj][r];
        if (BIASMODE == 1) v += bias[m];
        Cg[(long)m * N + n] = (OUT_T)(v * alpha);
      }
    }
  }
}

// ---------------------------------------------------------------------------
// 128^2 4-wave GEMM — step 6 only (128 blocks). v8: same full-unroll +
// static-buffer fix. Ledger: prologue stages 0,1,2 (12 instrs). Top of tile
// t: vmcnt(8) retires tile t's 4 (oldest). Reads then stage(t+3) -> 12.
// ---------------------------------------------------------------------------
template <int BIASMODE, typename OUT_T, int NT>
__global__ __launch_bounds__(256) void gemm_mfma_bt(
    const __bf16* __restrict__ Ag, const __bf16* __restrict__ Bg,
    const float* __restrict__ bias, OUT_T* __restrict__ Cg,
    int M, int N, int K, long sA, long sB, long sC, float alpha,
    int ksl, long sSlice) {
  __shared__ __align__(16) __bf16 As[4][128][32];
  __shared__ __align__(16) __bf16 Bs[4][128][32];

  const int tid = threadIdx.x;
  const int n0 = blockIdx.x * 128;
  const int m0 = blockIdx.y * 128;
  const int bz = blockIdx.z;
  const int batch = bz / ksl;
  const int slice = bz - batch * ksl;
  const int kBeg = slice * (NT * 32);
  Ag += (long)batch * sA;
  Bg += (long)batch * sB;
  Cg += (long)batch * sC + (long)slice * sSlice;

  const int lane = tid & 63;
  const int w = tid >> 6;
  const int wr = w >> 1, wc = w & 1;
  const int l15 = lane & 15, quad = lane >> 4;

  const int srow = tid >> 2;
  const int scol = (tid & 3) * 8;
  const __bf16* Arow = Ag + (long)(m0 + srow) * K + scol;
  const __bf16* Brow = Bg + (long)(n0 + srow) * K + scol;

  f32x4 acc[4][4] = {};

  auto stageT = [&](int t) {
    const int b = t & 3;
    const int kk = kBeg + t * 32;
#pragma unroll
    for (int s = 0; s < 2; s++) {
      async_copy16(Arow + (long)s * 64 * K + kk,
                   (char*)&As[b][0][0] + s * 4096 + tid * 16);
      async_copy16(Brow + (long)s * 64 * K + kk,
                   (char*)&Bs[b][0][0] + s * 4096 + tid * 16);
    }
  };

  stageT(0);
  stageT(1);
  stageT(2);

#pragma unroll
  for (int t = 0; t < NT; t++) {
    if (t < NT - 2)
      asm volatile("s_waitcnt vmcnt(8)" ::: "memory");
    else if (t == NT - 2)
      asm volatile("s_waitcnt vmcnt(4)" ::: "memory");
    else
      asm volatile("s_waitcnt vmcnt(0)" ::: "memory");
    __builtin_amdgcn_s_barrier();
    __builtin_amdgcn_sched_barrier(0);

    const int b = t & 3;
    bf16x8 af[4], bfr[4];
#pragma unroll
    for (int u = 0; u < 4; u++) {
      af[u]  = *(const bf16x8*)&As[b][wr * 64 + u * 16 + l15][quad * 8];
      bfr[u] = *(const bf16x8*)&Bs[b][wc * 64 + u * 16 + l15][quad * 8];
    }
    __builtin_amdgcn_sched_barrier(0);  // reads stay above the stage issue
    if (t + 3 < NT) stageT(t + 3);

    __builtin_amdgcn_s_setprio(1);
#pragma unroll
    for (int ti = 0; ti < 4; ti++)
#pragma unroll
      for (int tj = 0; tj < 4; tj++)
        acc[ti][tj] = __builtin_amdgcn_mfma_f32_16x16x32_bf16(
            af[ti], bfr[tj], acc[ti][tj], 0, 0, 0);
    __builtin_amdgcn_s_setprio(0);
  }

#pragma unroll
  for (int ti = 0; ti < 4; ti++) {
#pragma unroll
    for (int tj = 0; tj < 4; tj++) {
#pragma unroll
      for (int r = 0; r < 4; r++) {
        const int m = m0 + wr * 64 + ti * 16 + quad * 4 + r;
        const int n = n0 + wc * 64 + tj * 16 + l15;
        float v = acc[ti][tj][r];
        if (BIASMODE == 1) v += bias[m];
        Cg[(long)m * N + n] = (OUT_T)(v * alpha);
      }
    }
  }
}

// ---------------------------------------------------------------------------
// Dual softmax over bf16 logit rows [B,1024,HWN] in d_out.
// Row c<512 (B-logits): write normalized bf16 row to bm[b,c,:].
// Row c>=512 (V-logits): write back in place (av).
// ---------------------------------------------------------------------------
__global__ __launch_bounds__(256) void softmax_dual_bf16(
    __bf16* __restrict__ logits, __bf16* __restrict__ bm) {
  const int row = blockIdx.x;                 // 0..8191
  const int b = row >> 10, c = row & 1023;
  __bf16* src = logits + ((long)b * 1024 + c) * HWN;
  __bf16* dst = (c < 512) ? (bm + ((long)b * 512 + c) * HWN) : src;
  const int tid = threadIdx.x;

  const bf16x8* p = reinterpret_cast<const bf16x8*>(src);
  bf16x8* q = reinterpret_cast<bf16x8*>(dst);

  float v[16];
  float vmax = -3.0e38f;
#pragma unroll
  for (int i = 0; i < 2; i++) {
    bf16x8 t = p[tid + i * 256];
#pragma unroll
    for (int j = 0; j < 8; j++) {
      v[i * 8 + j] = (float)t[j];
      vmax = fmaxf(vmax, v[i * 8 + j]);
    }
  }
#pragma unroll
  for (int off = 32; off > 0; off >>= 1)
    vmax = fmaxf(vmax, __shfl_xor(vmax, off, 64));

  __shared__ float red[4];
  const int wid = tid >> 6;
  if ((tid & 63) == 0) red[wid] = vmax;
  __syncthreads();
  vmax = fmaxf(fmaxf(red[0], red[1]), fmaxf(red[2], red[3]));
  __syncthreads();

  float s = 0.f;
#pragma unroll
  for (int i = 0; i < 16; i++) {
    v[i] = expf(v[i] - vmax);
    s += v[i];
  }
#pragma unroll
  for (int off = 32; off > 0; off >>= 1) s += __shfl_xor(s, off, 64);
  if ((tid & 63) == 0) red[wid] = s;
  __syncthreads();
  s = (red[0] + red[1]) + (red[2] + red[3]);

  const float inv = 1.0f / s;
#pragma unroll
  for (int i = 0; i < 2; i++) {
    bf16x8 o;
#pragma unroll
    for (int j = 0; j < 8; j++) o[j] = (__bf16)(v[i * 8 + j] * inv);
    q[tid + i * 256] = o;
  }
}

// ---------------------------------------------------------------------------
// Reduce bf16 split-K partials (8 slices of 262144 elems per batch, batch
// stride 2097152) -> bf16 Mb. One thread = 8 output elems.
// ---------------------------------------------------------------------------
__global__ __launch_bounds__(256) void reduce_partials8b(
    const __bf16* __restrict__ P, __bf16* __restrict__ out) {
  const long i = ((long)blockIdx.x * 256 + threadIdx.x) * 8;  // < 2M
  const int b = (int)(i >> 18);
  const long il = i & 262143;
  const __bf16* p = P + (long)b * 2097152 + il;
  float s[8] = {};
#pragma unroll
  for (int sl = 0; sl < 8; sl++) {
    bf16x8 t = *(const bf16x8*)&p[(long)sl * 262144];
#pragma unroll
    for (int j = 0; j < 8; j++) s[j] += (float)t[j];
  }
  bf16x8 o;
#pragma unroll
  for (int j = 0; j < 8; j++) o[j] = (__bf16)s[j];
  *(bf16x8*)&out[i] = o;
}

// ---------------------------------------------------------------------------
// z<8:  x (fp32 [C,HW] batch z) -> xb (bf16 same layout) + xT (bf16 [HW,C]).
// z==8: weight/bias conversion (wB,wV -> wBVb stacked; wA -> wAb; bBV pack).
// float4 global loads, bf16x4 global stores on BOTH outputs (G13).
// ---------------------------------------------------------------------------
__global__ __launch_bounds__(256) void convert_all(
    const float* __restrict__ x, __bf16* __restrict__ xb,
    __bf16* __restrict__ xT, const float* __restrict__ wA,
    const float* __restrict__ wB, const float* __restrict__ wV,
    const float* __restrict__ bB, const float* __restrict__ bV,
    __bf16* __restrict__ wAb, __bf16* __restrict__ wBVb,
    float* __restrict__ bBV) {
  if (blockIdx.z == 8) {
    const int t = blockIdx.y * 64 + blockIdx.x;  // 0..511
    const int grp = t >> 7;                      // 128 blocks per matrix
    const int r = t & 127;
    if (grp == 3) {
      if (r == 0) {
#pragma unroll
        for (int j = 0; j < 4; j++) {
          const int i = threadIdx.x * 4 + j;
          bBV[i] = (i < 512) ? bB[i] : bV[i - 512];
        }
      }
      return;
    }
    const float* in = grp == 0 ? wB : (grp == 1 ? wV : wA);
    __bf16* o = grp == 0 ? wBVb : (grp == 1 ? wBVb + 262144 : wAb);
    const long base = (long)r * 2048 + threadIdx.x * 8;  // 2048 elems/block
    float4 v0 = *(const float4*)&in[base];
    float4 v1 = *(const float4*)&in[base + 4];
    bf16x8 ob;
    ob[0] = (__bf16)v0.x; ob[1] = (__bf16)v0.y; ob[2] = (__bf16)v0.z;
    ob[3] = (__bf16)v0.w; ob[4] = (__bf16)v1.x; ob[5] = (__bf16)v1.y;
    ob[6] = (__bf16)v1.z; ob[7] = (__bf16)v1.w;
    *(bf16x8*)&o[base] = ob;
    return;
  }

  __shared__ __bf16 t[64][72];
  const int j0 = blockIdx.x * 64;   // hw tile
  const int c0 = blockIdx.y * 64;   // c tile
  const long bofs = (long)blockIdx.z * CC * HWN;
  const int cl = threadIdx.x & 15;  // 4-float column group
  const int rw = threadIdx.x >> 4;  // 0..15

#pragma unroll
  for (int p = 0; p < 4; p++) {
    const int i = p * 16 + rw;      // row in tile (c-dim)
    const float4 v =
        *(const float4*)&x[bofs + (long)(c0 + i) * HWN + j0 + cl * 4];
    bf16x4 ob;
    ob[0] = (__bf16)v.x; ob[1] = (__bf16)v.y;
    ob[2] = (__bf16)v.z; ob[3] = (__bf16)v.w;
    *(bf16x4*)&xb[bofs + (long)(c0 + i) * HWN + j0 + cl * 4] = ob;
    t[cl * 4 + 0][i] = ob[0];
    t[cl * 4 + 1][i] = ob[1];
    t[cl * 4 + 2][i] = ob[2];
    t[cl * 4 + 3][i] = ob[3];
  }
  __syncthreads();
#pragma unroll
  for (int p = 0; p < 4; p++) {
    const int jj = p * 16 + rw;     // row in xT tile (hw-dim)
    bf16x4 o;
    o[0] = t[jj][cl * 4 + 0];
    o[1] = t[jj][cl * 4 + 1];
    o[2] = t[jj][cl * 4 + 2];
    o[3] = t[jj][cl * 4 + 3];
    *(bf16x4*)&xT[bofs + (long)(j0 + jj) * CC + c0 + cl * 4] = o;
  }
}

// bf16 transpose: out[b*sOut + j*CC + c] = in[b*sIn + c*ldIn + j]
__global__ __launch_bounds__(256) void transpose_bf16_s(
    const __bf16* __restrict__ in, __bf16* __restrict__ out, int ldIn,
    long sIn, long sOut) {
  __shared__ __bf16 t[64][66];
  const int j0 = blockIdx.x * 64;
  const int c0 = blockIdx.y * 64;
  const int j = threadIdx.x & 63;
  const int g = threadIdx.x >> 6;

#pragma unroll
  for (int r = 0; r < 16; r++) {
    const int i = r * 4 + g;
    t[j][i] = in[(long)blockIdx.z * sIn + (long)(c0 + i) * ldIn + j0 + j];
  }
  __syncthreads();
#pragma unroll
  for (int r = 0; r < 16; r++) {
    const int jj = r * 4 + g;
    out[(long)blockIdx.z * sOut + (long)(j0 + jj) * CC + c0 + j] = t[jj][j];
  }
}

// ---------------------------------------------------------------------------
// Plan:
//  0. convert_all: x->xb,xT; weights->bf16 (stacked wBV); biases packed
//  1. logits = wBV·x + bBV  (M=1024)  [gemm256]      -> d_out bf16 [B,1024,HW]
//  2. softmax_dual: B-rows -> bm (ws), V-rows -> in place (av)
//  3. transpose av -> avT into xT region (xT dead)
//  4. M partials split-K=8 (A=bm,B=xb) [gemm256]     -> d_out bf16 (32 MiB)
//  5. reduce -> Mb bf16
//  6. gdT = (wA·M^T + bA)/HW (A=wAb,B=Mb) [gemm128]  -> gdT bf16
//  7. out = gdT·avT          (A=gdT,B=xT) [gemm256]  -> d_out fp32 (full 64MB)
// ---------------------------------------------------------------------------
extern "C" void kernel_launch(void* const* d_in, const int* in_sizes, int n_in,
                              void* d_out, int out_size, void* d_ws,
                              size_t ws_size, hipStream_t stream) {
  const float* x  = (const float*)d_in[0];
  const float* wA = (const float*)d_in[1];
  const float* bA = (const float*)d_in[2];
  const float* wB = (const float*)d_in[3];
  const float* bB = (const float*)d_in[4];
  const float* wV = (const float*)d_in[5];
  const float* bV = (const float*)d_in[6];
  float* out = (float*)d_out;

  const size_t nBCHW = (size_t)BB * CC * HWN;   // 16M
  const size_t nBCC  = (size_t)BB * CC * CC;    // 2M
  __bf16* xb   = (__bf16*)d_ws;          // [B,C,HW]
  __bf16* xT   = xb + nBCHW;             // [B,HW,C]; later avT
  __bf16* bm   = xT + nBCHW;             // [B,C,HW]
  __bf16* Mb   = bm + nBCHW;             // [B,C,C]
  __bf16* gdT  = Mb + nBCC;              // [B,C,C]
  __bf16* wBVb = gdT + nBCC;             // [1024,512]
  __bf16* wAb  = wBVb + (size_t)1024 * CC;
  float*  bBV  = (float*)(wAb + (size_t)CC * CC);  // [1024]

  const long sBC_HW = (long)CC * HWN;    // 2097152
  const long sCC = (long)CC * CC;        // 262144

  convert_all<<<dim3(HWN / 64, CC / 64, BB + 1), 256, 0, stream>>>(
      x, xb, xT, wA, wB, wV, bB, bV, wAb, wBVb, bBV);

  __bf16* logits = (__bf16*)d_out;       // [B,1024,HW] bf16 == 64 MiB

  // 1. merged logits GEMM (M=1024): rows 0-511 B-logits, 512-1023 V-logits
  gemm256_mfma_bt<1, __bf16, 16>
      <<<dim3(HWN / 256, 1024 / 256, BB), 512, 0, stream>>>(
          wBVb, xT, bBV, logits, 1024, HWN, CC, 0, sBC_HW, (long)1024 * HWN,
          1.0f, 1, 0);
  // 2. dual softmax
  softmax_dual_bf16<<<dim3(BB * 1024), 256, 0, stream>>>(logits, bm);
  // 3. avT (av rows live at logits + b*4194304 + 2097152 + c*4096)
  transpose_bf16_s<<<dim3(HWN / 64, CC / 64, BB), 256, 0, stream>>>(
      logits + 2097152, xT, HWN, (long)1024 * HWN, (long)HWN * CC);
  // 4. M split-K=8 partials -> d_out as bf16: batch 2097152, slice 262144
  gemm256_mfma_bt<0, __bf16, 16><<<dim3(CC / 256, CC / 256, BB * 8), 512, 0,
                                   stream>>>(bm, xb, nullptr, (__bf16*)out,
                                             CC, CC, HWN, sBC_HW, sBC_HW,
                                             (long)2097152, 1.0f, 8,
                                             (long)262144);
  // 5. reduce -> Mb
  reduce_partials8b<<<dim3(1024), 256, 0, stream>>>((const __bf16*)out, Mb);
  // 6. gdT = (wA @ M^T + bA)/HW  (small grid -> 128^2 kernel)
  gemm_mfma_bt<1, __bf16, 16><<<dim3(CC / 128, CC / 128, BB), 256, 0,
                                stream>>>(wAb, Mb, bA, gdT, CC, CC, CC, 0,
                                          sCC, sCC, 1.0f / (float)HWN, 1, 0);
  // 7. out = gdT @ avT -> d_out (fp32, overwrites everything)
  gemm256_mfma_bt<0, float, 16>
      <<<dim3(HWN / 256, CC / 256, BB), 512, 0, stream>>>(
          gdT, xT, nullptr, out, CC, HWN, CC, sCC, sBC_HW, sBC_HW, 1.0f, 1,
          0);
}